// Round 4
// baseline (411.592 us; speedup 1.0000x reference)
//
#include <hip/hip_runtime.h>
#include <math.h>

// Problem: IN=8192, HID=8192, OUT=1024, fp32.
// out = spiking_layer(spiking_layer(exp(x), W1), W2)
//
// R6 (resubmit after infra failure): 4 kernels (2 per layer). Per layer:
//   fused : blocks [0,RANKB) = partial stable ranks (plain stores to
//           per-(seg,jtile) slots -> no zeroing, no atomics; exp inline).
//           blocks [RANKB,..) = one W row each: issue row loads, stage
//           z=exp(x) (or z2) into LDS while loads fly, in-block Zsum'/jmax
//           (Zsum' feeds ONLY comparisons -> association-free; jmax is an
//           integer-exact max), Wsum with the EXACT R5 reduction shape,
//           pass B {C, Sw-bw, wj} vs tmp'.
//   scanC : single block: sum 8 rank partials -> full rank (permutation),
//           scatter z by rank, blocked scan (EXACT R5 association, csZ in
//           LDS), per-row branch logic -> outputs.
// All float ops reaching `out` bits are byte-identical to the R5 kernel that
// measured absmax 0.0: Wsum reduction, pass-B Sw/bw accumulation order,
// csZ scan association, Wc = Wsum - wj, final Wc*Zc/(Wc-1).

static constexpr int NN     = 8192;   // columns of both W's
static constexpr int HID    = 8192;
static constexpr int OUTN   = 1024;
static constexpr int SEGS   = 8;
static constexpr int SEGLEN = NN / SEGS;     // 1024
static constexpr int RANKB  = 32 * SEGS;     // 256 rank blocks

// Total order on floats matching < (negatives, inf handled).
__device__ inline unsigned f2ord(float f) {
    unsigned u = __float_as_uint(f);
    return (u & 0x80000000u) ? ~u : (u | 0x80000000u);
}
__device__ inline unsigned long long sortkey(float f, int j) {
    return (((unsigned long long)f2ord(f)) << 13) | (unsigned)j;   // j < 8192
}

// Fused rank + W-stream.
//   b <  RANKB : block (jt,seg) counts, for each j in jt's 256-wide tile, how
//                many keys in segment seg are < key(j). Plain store.
//   b >= RANKB : one output row; stream the row once (coalesced float4 ->
//                regs), stage z in LDS, in-block Zsum'/jmax, Wsum (EXACT R5
//                reduction), pass B {C, Sw, restricted key-argmax} vs tmp'.
template <bool DOEXP>
__global__ __launch_bounds__(256)
void fused_kernel(const float* __restrict__ W,
                  const float* __restrict__ src,
                  int* __restrict__ rank_part,
                  float4* __restrict__ stats) {
    __shared__ __align__(16) char smem[NN * 4];          // 32 KB union
    float* z_l = (float*)smem;
    unsigned long long* keys = (unsigned long long*)smem; // rank role: 8 KB
    __shared__ float red4[4], redz[4];
    __shared__ unsigned long long redk[4];
    __shared__ float s_wsum, s_tmp;
    __shared__ int s_jmax;
    __shared__ int   sc_i[4];
    __shared__ float ssw[4], sbw[4];
    __shared__ unsigned long long sbk[4];

    int b = blockIdx.x, t = threadIdx.x;
    if (b < RANKB) {
        int jt = b >> 3, seg = b & 7;
        int j = jt * 256 + t;
        float zj = src[j];
        if (DOEXP) zj = expf(zj);
        unsigned long long K = sortkey(zj, j);
        int base = seg * SEGLEN;
        for (int i = t; i < SEGLEN; i += 256) {
            float zv = src[base + i];
            if (DOEXP) zv = expf(zv);
            keys[i] = sortkey(zv, base + i);
        }
        __syncthreads();
        int cnt = 0;
#pragma unroll 8
        for (int i = 0; i < SEGLEN; ++i) cnt += (keys[i] < K) ? 1 : 0;   // LDS broadcast
        rank_part[seg * NN + j] = cnt;                   // one writer per slot
        return;
    }
    int o = b - RANKB;
    int lane = t & 63, wv = t >> 6;
    const float4* row4 = (const float4*)(W + (size_t)o * NN);

    // Issue the HBM row loads first so they fly during z staging.
    float4 w[8];
#pragma unroll
    for (int i = 0; i < 8; ++i) w[i] = row4[t + i * 256];

    // Stage z into LDS; per-thread Zsum' partial and key-argmax.
    const float4* s4 = (const float4*)src;
    float4* z4l = (float4*)z_l;
    float sz = 0.f;
    unsigned long long zk = 0ull;
#pragma unroll
    for (int i = 0; i < 8; ++i) {
        int q = t + i * 256;
        float4 zq = s4[q];
        if (DOEXP) { zq.x = expf(zq.x); zq.y = expf(zq.y); zq.z = expf(zq.z); zq.w = expf(zq.w); }
        z4l[q] = zq;
        sz += (zq.x + zq.y) + (zq.z + zq.w);
        int jb = q * 4;
        unsigned long long k0 = sortkey(zq.x, jb), k1 = sortkey(zq.y, jb + 1);
        unsigned long long k2 = sortkey(zq.z, jb + 2), k3 = sortkey(zq.w, jb + 3);
        if (k0 > zk) zk = k0;
        if (k1 > zk) zk = k1;
        if (k2 > zk) zk = k2;
        if (k3 > zk) zk = k3;
    }

    // Pass A sum: EXACT R5 association (i order, (x+y)+(z+w)).
    float s = 0.f;
#pragma unroll
    for (int i = 0; i < 8; ++i) s += (w[i].x + w[i].y) + (w[i].z + w[i].w);
    for (int off = 32; off > 0; off >>= 1) {
        s  += __shfl_down(s, off);               // Wsum: exact R5 shape
        sz += __shfl_down(sz, off);              // Zsum': comparison-only
        unsigned long long ok = __shfl_down(zk, off);
        if (ok > zk) zk = ok;                    // jmax: integer-exact
    }
    if (lane == 0) { red4[wv] = s; redz[wv] = sz; redk[wv] = zk; }
    __syncthreads();
    if (t == 0) {
        float Wsum = (red4[0] + red4[1]) + (red4[2] + red4[3]);   // exact R5
        float Zs = ((redz[0] + redz[1]) + (redz[2] + redz[3]));
        unsigned long long B = redk[0];
        if (redk[1] > B) B = redk[1];
        if (redk[2] > B) B = redk[2];
        if (redk[3] > B) B = redk[3];
        s_wsum = Wsum;
        s_tmp = Wsum * Zs / (Wsum - 1.0f);       // tmp' : comparison-only
        s_jmax = (int)(B & 0x1FFFull);
    }
    __syncthreads();
    float tmp = s_tmp;

    // Pass B: count / restricted sum / restricted key-argmax vs z in LDS.
    const float4* z4 = (const float4*)z_l;
    int c = 0;
    float Sw = 0.f;
    unsigned long long bk = 0ull;
    float bw = 0.f;
#pragma unroll
    for (int i = 0; i < 8; ++i) {
        int q = t + i * 256;
        float4 zq = z4[q];
        float zz[4] = {zq.x, zq.y, zq.z, zq.w};
        float ww[4] = {w[i].x, w[i].y, w[i].z, w[i].w};
        int jb = q * 4;
#pragma unroll
        for (int l = 0; l < 4; ++l) {
            if (zz[l] <= tmp) {
                ++c;
                Sw += ww[l];
                unsigned long long K = sortkey(zz[l], jb + l);
                if (K > bk) { bk = K; bw = ww[l]; }
            }
        }
    }
    for (int off = 32; off > 0; off >>= 1) {
        c  += __shfl_down(c, off);
        Sw += __shfl_down(Sw, off);
        unsigned long long ok = __shfl_down(bk, off);
        float ow = __shfl_down(bw, off);
        if (ok > bk) { bk = ok; bw = ow; }
    }
    if (lane == 0) { sc_i[wv] = c; ssw[wv] = Sw; sbk[wv] = bk; sbw[wv] = bw; }
    __syncthreads();
    if (t == 0) {
        int C = 0; float SwT = 0.f; unsigned long long bkT = 0ull; float bwT = 0.f;
        for (int v = 0; v < 4; ++v) {
            C += sc_i[v];
            SwT += ssw[v];
            if (sbk[v] > bkT) { bkT = sbk[v]; bwT = sbw[v]; }
        }
        float wj = W[(size_t)o * NN + s_jmax];   // same load as R5's jmax path
        float4 st;
        st.x = s_wsum;
        st.y = wj;
        st.z = SwT - bwT;                        // general-path Wc
        st.w = __int_as_float(C);
        stats[o] = st;
    }
}

// Single block, 1024 threads: sum 8 rank partials -> full rank, scatter by
// rank, blocked scan (EXACT R5 association) with csZ in LDS, per-row branch
// logic -> outputs.
template <bool DOEXP>
__global__ void scancombine_kernel(const float* __restrict__ src,
                                   const int* __restrict__ rank_part,
                                   const float4* __restrict__ stats,
                                   int rows,
                                   float* __restrict__ outv) {
    __shared__ float zs_l[NN];                    // 32 KB
    __shared__ float csZ_l[NN];                   // 32 KB
    __shared__ float wsum_s[16], woff_s[16];
    int t = threadIdx.x;
#pragma unroll
    for (int i = 0; i < 8; ++i) {
        int j = t + i * 1024;                     // coalesced
        int r = 0;
#pragma unroll
        for (int s = 0; s < SEGS; ++s) r += rank_part[s * NN + j];
        float z = src[j];
        if (DOEXP) z = expf(z);
        zs_l[r] = z;                              // r is a permutation of [0,NN)
    }
    __syncthreads();
    int lane = t & 63, wv = t >> 6;               // 16 waves
    int base = t * 8;
    float v[8], s = 0.f;
#pragma unroll
    for (int i = 0; i < 8; ++i) { v[i] = zs_l[base + i]; s += v[i]; }
    float sc = s;                                 // inclusive wave scan of thread sums
    for (int off = 1; off < 64; off <<= 1) {
        float up = __shfl_up(sc, off);
        if (lane >= off) sc += up;
    }
    if (lane == 63) wsum_s[wv] = sc;
    __syncthreads();
    if (t == 0) {
        float acc = 0.f;
        for (int w = 0; w < 16; ++w) { woff_s[w] = acc; acc += wsum_s[w]; }
    }
    __syncthreads();
    float run = woff_s[wv] + (sc - s);            // exclusive base for this thread
#pragma unroll
    for (int i = 0; i < 8; ++i) { csZ_l[base + i] = run; run += v[i]; }
    __syncthreads();

    // Combine: per-row branch logic (exact R5 decision tree + arithmetic).
    int rpt = rows >> 10;
    for (int i = 0; i < rpt; ++i) {
        int o = t + i * 1024;
        float4 st = stats[o];
        float Wsum = st.x, wj = st.y, SwB = st.z;
        int C = __float_as_int(st.w);
        bool fc = Wsum > 1.0f;
        int k = -1; bool empty = false;
        if (fc) {
            if (C >= 1) k = NN - 1; else empty = true;
        } else {
            if (C < NN) {
                if (C == 0) k = NN - 1;
                else if (C == 1) empty = true;
                else k = C - 1;
            } else empty = true;
        }
        float val;
        if (empty) val = __builtin_inff();
        else {
            float Wc = (k == NN - 1) ? (Wsum - wj) : SwB;
            val = Wc * csZ_l[k] / (Wc - 1.0f);
        }
        outv[o] = val;
    }
}

extern "C" void kernel_launch(void* const* d_in, const int* in_sizes, int n_in,
                              void* d_out, int out_size, void* d_ws, size_t ws_size,
                              hipStream_t stream) {
    const float* x  = (const float*)d_in[0];
    const float* W1 = (const float*)d_in[1];   // [8192, 8192]
    const float* W2 = (const float*)d_in[2];   // [1024, 8192]
    float* out = (float*)d_out;                // [1024]

    char* ws = (char*)d_ws;
    size_t off = 0;
    auto alloc = [&](size_t bytes) -> void* {
        void* p = ws + off;
        off += (bytes + 255) & ~(size_t)255;
        return p;
    };
    float*  z2         = (float*)alloc((size_t)NN * 4);
    float4* stats1     = (float4*)alloc((size_t)HID * 16);
    float4* stats2     = (float4*)alloc((size_t)OUTN * 16);
    int*    rank1_part = (int*)alloc((size_t)SEGS * NN * 4);   // plain stores, no zeroing
    int*    rank2_part = (int*)alloc((size_t)SEGS * NN * 4);

    // Layer 1
    fused_kernel<true><<<RANKB + HID, 256, 0, stream>>>(W1, x, rank1_part, stats1);
    scancombine_kernel<true><<<1, 1024, 0, stream>>>(x, rank1_part, stats1, HID, z2);
    // Layer 2
    fused_kernel<false><<<RANKB + OUTN, 256, 0, stream>>>(W2, z2, rank2_part, stats2);
    scancombine_kernel<false><<<1, 1024, 0, stream>>>(z2, rank2_part, stats2, OUTN, out);
}